// Round 2
// baseline (19343.977 us; speedup 1.0000x reference)
//
#include <hip/hip_runtime.h>
#include <cstdint>
#include <cmath>

// ============================================================================
// Bidirectional 2-layer GRU, B=64 S=1024 I=H=512, output = last-step concat @ fc.
//
//  - forward half  : 1024-step recurrence through both layers, persistent kernel.
//  - backward half : only scan index 0 survives the final slice => ONE step per
//                    layer with h0=0 => h = (1-sigmoid(xg1)) * tanh(xg2).
//
// Persistent kernel: 256 blocks x 256 threads, 160KB LDS => 1 block/CU.
// Block (layer, bg, slice) owns rows [bg*16,+16) x cols [slice*16,+16).
// Numerics: activations split hi+lo bf16; n-gate weights also carry a lo
// residual plane (7 MFMAs per fragment) so only r/z weight rounding (damped by
// sigmoid' <= 0.25) injects error. Sync: monotonic counters cnt[layer][bg][T],
// relaxed spin + __threadfence, WITH TIMEOUT+POISON so the kernel can never
// hang indefinitely (wrong-but-terminating on residency failure).
// h ring buffers: 4 planes deep so layer-1 only waits on c2[T-3] (off the
// critical path); per-step critical path = layer-1 self handshake only.
// ============================================================================

typedef __attribute__((ext_vector_type(8))) short bf16x8;
typedef __attribute__((ext_vector_type(4))) float f32x4;

#define DEV static __device__ __forceinline__

DEV unsigned short f2bf(float f) {
  union { float f; uint32_t u; } v; v.f = f;
  uint32_t u = v.u;
  uint32_t rnd = ((u >> 16) & 1u) + 0x7fffu;   // round-to-nearest-even
  return (unsigned short)((u + rnd) >> 16);
}
DEV float bf2f(unsigned short h) {
  union { uint32_t u; float f; } v; v.u = ((uint32_t)h) << 16;
  return v.f;
}
DEV float sigmoidf_(float x) { return 1.f / (1.f + expf(-x)); }

static constexpr int Ss = 1024, Ii = 512;

// ---- workspace layout (bytes) ----
static constexpr size_t WIMG_PER_LS = 131072;                 // 96KB hi + 32KB n-lo
static constexpr size_t OFF_WIMG = 0;
static constexpr size_t WIMG_BYTES = (size_t)64 * WIMG_PER_LS;  // 8 MB
static constexpr size_t OFF_H1  = OFF_WIMG + WIMG_BYTES;      // 4 planes x (hi|lo) [64][512] bf16
static constexpr size_t OFF_H2  = OFF_H1 + 524288;
static constexpr size_t OFF_CNT = OFF_H2 + 524288;            // int[2][4][1026]
static constexpr size_t OFF_H2F = OFF_CNT + 33024;            // f32 [64][512]
static constexpr size_t OFF_HB1 = OFF_H2F + 131072;
static constexpr size_t OFF_HB2 = OFF_HB1 + 131072;
static constexpr size_t WS_NEED = OFF_HB2 + 131072;

// ============================================================================
// Weight prep: per (layer,slice) image, 65536 bf16:
//   [0,49152)    hi : m(2: Wi,Wh) * 24576 + kg(64)*384 + c(48: g*16+cc)*8 + kr(8)
//   [49152,65536) n-gate lo residual: m*8192 + kg*128 + cc(16)*8 + kr
// ============================================================================
__global__ __launch_bounds__(256) void prep_weights(const float* __restrict__ Wi,
                                                    const float* __restrict__ Wh,
                                                    unsigned short* __restrict__ img) {
  uint32_t idx = blockIdx.x * 256 + threadIdx.x;          // < 4,194,304
  uint32_t ls = idx >> 16;                                // layer*32+slice
  uint32_t off = idx & 65535u;
  int l = (int)(ls >> 5), s = (int)(ls & 31);
  int m, g, cc, kg, kr;
  bool lo = off >= 49152u;
  if (!lo) {
    m = (int)(off / 24576u); uint32_t r = off % 24576u;
    kg = (int)(r / 384u); r %= 384u;
    int c = (int)(r >> 3); kr = (int)(r & 7u);
    g = c >> 4; cc = c & 15;
  } else {
    uint32_t o2 = off - 49152u;
    m = (int)(o2 >> 13); uint32_t r = o2 & 8191u;
    kg = (int)(r >> 7); r &= 127u;
    cc = (int)(r >> 3); kr = (int)(r & 7u);
    g = 2;
  }
  int h = s * 16 + cc, k = kg * 8 + kr;
  const float* W = m ? Wh : Wi;                           // [L][D][3][512][512], d=0
  float v = W[((size_t)(l * 6 + g) * 512 + k) * 512 + h];
  unsigned short hv = f2bf(v);
  if (lo) hv = f2bf(v - bf2f(hv));
  img[(size_t)ls * 65536 + off] = hv;
}

// zero h rings; init counters (slot 0 done everywhere; layer-2 slot 1 too)
__global__ __launch_bounds__(256) void init_state(uint32_t* __restrict__ hz,
                                                  int* __restrict__ cnt) {
  int tid = blockIdx.x * 256 + threadIdx.x;
  if (tid < 262144) hz[tid] = 0u;                         // h1+h2 = 1MB
  if (tid < 8208) {
    int lay  = tid / 4104;
    int slot = tid % 1026;
    cnt[tid] = (slot == 0 || (lay == 1 && slot == 1)) ? 32 : 0;
  }
}

// ---- hang-proof wait: relaxed spin; on timeout poison both counter arrays ----
DEV void poison_arr(int* a) {
  for (int i = 0; i < 1026; ++i)
    __hip_atomic_fetch_add(a + i, 1 << 20, __ATOMIC_RELAXED, __HIP_MEMORY_SCOPE_AGENT);
}
DEV void waitge32(int* p, int* pa, int* pb) {
  int spins = 0;
  while (__hip_atomic_load(p, __ATOMIC_RELAXED, __HIP_MEMORY_SCOPE_AGENT) < 32) {
    __builtin_amdgcn_s_sleep(1);
    if (++spins > (1 << 21)) { poison_arr(pa); poison_arr(pb); return; }
  }
}

// ============================================================================
// Persistent forward recurrence.
// LDS: [0,98304) W hi (Wi@0, Wh@49152) ; [98304,131072) n-lo (Wi@+0, Wh@+16384)
//      [131072,163840) x hi/lo staging (layer1) / rbuf f32[4][6][256] (both)
// ============================================================================
__global__ __launch_bounds__(256) void gru_persistent(const float* __restrict__ x,
                                                      const float* __restrict__ bias,
                                                      unsigned char* __restrict__ ws) {
  __shared__ unsigned char lds[163840];
  const int tid  = threadIdx.x;
  const int lane = tid & 63;
  const int wv   = tid >> 6;
  const int bid  = blockIdx.x;
  const int layer = bid >> 7;
  const int bg    = (bid >> 5) & 3;
  const int slice = bid & 31;
  const int l15 = lane & 15, q = lane >> 4;

  { // stage weight image (128KB) into LDS once
    const f32x4* src = (const f32x4*)(ws + OFF_WIMG + (size_t)(layer * 32 + slice) * WIMG_PER_LS);
    f32x4* dst = (f32x4*)lds;
    for (int i = tid; i < 8192; i += 256) dst[i] = src[i];
  }
  __syncthreads();

  unsigned short* h1 = (unsigned short*)(ws + OFF_H1);
  unsigned short* h2 = (unsigned short*)(ws + OFF_H2);
  int* cnt = (int*)(ws + OFF_CNT);
  int* c1 = cnt + bg * 1026;
  int* c2 = cnt + (4 + bg) * 1026;
  float* h2f  = (float*)(ws + OFF_H2F);
  float* rbuf = (float*)(lds + 131072);
  unsigned char* xlds = lds + 131072;

  const int e_col = tid >> 4, e_row = tid & 15;
  const int row_g = bg * 16 + e_row;
  const int col_g = slice * 16 + e_col;
  const float b0 = bias[(size_t)(layer * 6 + 0) * 512 + col_g];
  const float b1 = bias[(size_t)(layer * 6 + 1) * 512 + col_g];
  const float b2 = bias[(size_t)(layer * 6 + 2) * 512 + col_g];

  float hprev = 0.f;

#define MFMA7(AHI, ALO, WB, WL, A0, A1, A2)                                      \
  {                                                                              \
    bf16x8 bq0 = *(const bf16x8*)(WB);                                           \
    bf16x8 bq1 = *(const bf16x8*)((WB) + 256);                                   \
    bf16x8 bq2 = *(const bf16x8*)((WB) + 512);                                   \
    bf16x8 bql = *(const bf16x8*)(WL);                                           \
    A0 = __builtin_amdgcn_mfma_f32_16x16x32_bf16(AHI, bq0, A0, 0, 0, 0);         \
    A0 = __builtin_amdgcn_mfma_f32_16x16x32_bf16(ALO, bq0, A0, 0, 0, 0);         \
    A1 = __builtin_amdgcn_mfma_f32_16x16x32_bf16(AHI, bq1, A1, 0, 0, 0);         \
    A1 = __builtin_amdgcn_mfma_f32_16x16x32_bf16(ALO, bq1, A1, 0, 0, 0);         \
    A2 = __builtin_amdgcn_mfma_f32_16x16x32_bf16(AHI, bq2, A2, 0, 0, 0);         \
    A2 = __builtin_amdgcn_mfma_f32_16x16x32_bf16(ALO, bq2, A2, 0, 0, 0);         \
    A2 = __builtin_amdgcn_mfma_f32_16x16x32_bf16(AHI, bql, A2, 0, 0, 0);         \
  }

#define REDUCE_AND_GATE()                                                        \
  {                                                                              \
    float* bp = rbuf + (size_t)wv * 1536 + l15 * 16 + q * 4;                     \
    *(f32x4*)(bp + 0)    = ax0;  *(f32x4*)(bp + 256)  = ax1;                     \
    *(f32x4*)(bp + 512)  = ax2;  *(f32x4*)(bp + 768)  = ah0;                     \
    *(f32x4*)(bp + 1024) = ah1;  *(f32x4*)(bp + 1280) = ah2;                     \
  }                                                                              \
  __syncthreads();                                                               \
  float xg0 = 0, xg1 = 0, xg2 = 0, hg0 = 0, hg1 = 0, hg2 = 0;                    \
  _Pragma("unroll")                                                              \
  for (int w2 = 0; w2 < 4; ++w2) {                                               \
    const float* bb = rbuf + (size_t)w2 * 1536 + tid;                            \
    xg0 += bb[0];   xg1 += bb[256];  xg2 += bb[512];                             \
    hg0 += bb[768]; hg1 += bb[1024]; hg2 += bb[1280];                            \
  }                                                                              \
  float rr = sigmoidf_(xg0 + hg0 + b0);                                          \
  float zz = sigmoidf_(xg1 + hg1 + b1);                                          \
  float nn = tanhf(xg2 + b2 + rr * hg2);                                         \
  float hn = (1.f - zz) * nn + zz * hprev;                                       \
  hprev = hn;

  if (layer == 0) {
    const float* xrow = x + (size_t)(bg * 16) * Ss * Ii;
    for (int T = 1; T <= 1024; ++T) {
      const int t = T - 1;
      // stage x_t into LDS as swizzled hi/lo bf16 (no flag dependency)
      for (int j = 0; j < 32; ++j) {
        int idx = j * 256 + tid;
        int r = idx >> 9, k = idx & 511;
        float v = xrow[(size_t)r * Ss * Ii + (size_t)t * Ii + k];
        unsigned short hi = f2bf(v);
        unsigned short lo = f2bf(v - bf2f(hi));
        int off = (r * 64 + ((k >> 3) ^ (r & 7))) * 16 + (k & 7) * 2;
        *(unsigned short*)(xlds + off)         = hi;
        *(unsigned short*)(xlds + 16384 + off) = lo;
      }
      __syncthreads();
      f32x4 ax0{}, ax1{}, ax2{}, ah0{}, ah1{}, ah2{};
#pragma unroll
      for (int kk = 0; kk < 4; ++kk) {                     // accx = x_t . Wi1
        int kg = wv * 16 + kk * 4 + q;
        int so = (l15 * 64 + (kg ^ (l15 & 7))) * 16;
        bf16x8 ahi = *(const bf16x8*)(xlds + so);
        bf16x8 alo = *(const bf16x8*)(xlds + 16384 + so);
        const unsigned char* wb = lds + (size_t)kg * 768 + l15 * 16;
        const unsigned char* wl = lds + 98304 + (size_t)kg * 256 + l15 * 16;
        MFMA7(ahi, alo, wb, wl, ax0, ax1, ax2);
      }
      // wait: h1_{T-1} ready; layer-2 done with h1_{T-4} (plane reuse)
      if (tid == 0) {
        waitge32(c1 + (T - 1), c1, c2);
        waitge32(c2 + (T >= 3 ? T - 3 : 0), c1, c2);
        __threadfence();
      }
      __syncthreads();
      const unsigned short* hs = h1 + (size_t)((T - 1) & 3) * 65536 + (size_t)(bg * 16 + l15) * 512;
#pragma unroll
      for (int kk = 0; kk < 4; ++kk) {                     // acch = h1_{T-1} . Wh1
        int kg = wv * 16 + kk * 4 + q;
        bf16x8 ahi = *(const bf16x8*)(hs + kg * 8);
        bf16x8 alo = *(const bf16x8*)(hs + 32768 + kg * 8);
        const unsigned char* wb = lds + 49152 + (size_t)kg * 768 + l15 * 16;
        const unsigned char* wl = lds + 98304 + 16384 + (size_t)kg * 256 + l15 * 16;
        MFMA7(ahi, alo, wb, wl, ah0, ah1, ah2);
      }
      __syncthreads();                                     // xlds reads done -> rbuf
      REDUCE_AND_GATE();
      unsigned short hi = f2bf(hn);
      unsigned short lo = f2bf(hn - bf2f(hi));
      unsigned short* hd = h1 + (size_t)(T & 3) * 65536 + (size_t)row_g * 512 + col_g;
      hd[0] = hi; hd[32768] = lo;
      __syncthreads();                                     // stores drained
      if (tid == 0) {
        __threadfence();
        __hip_atomic_fetch_add(c1 + T, 1, __ATOMIC_RELAXED, __HIP_MEMORY_SCOPE_AGENT);
      }
    }
  } else {
    for (int T = 2; T <= 1025; ++T) {                      // computes h2_{T-1}
      if (tid == 0) {
        waitge32(c1 + (T - 1), c1, c2);
        waitge32(c2 + (T - 1), c1, c2);
        __threadfence();
      }
      __syncthreads();
      f32x4 ax0{}, ax1{}, ax2{}, ah0{}, ah1{}, ah2{};
      const unsigned short* as = h1 + (size_t)((T - 1) & 3) * 65536 + (size_t)(bg * 16 + l15) * 512;
      const unsigned short* hs = h2 + (size_t)((T - 2) & 3) * 65536 + (size_t)(bg * 16 + l15) * 512;
#pragma unroll
      for (int kk = 0; kk < 4; ++kk) {                     // xg = h1_{T-1} . Wi2
        int kg = wv * 16 + kk * 4 + q;
        bf16x8 ahi = *(const bf16x8*)(as + kg * 8);
        bf16x8 alo = *(const bf16x8*)(as + 32768 + kg * 8);
        const unsigned char* wb = lds + (size_t)kg * 768 + l15 * 16;
        const unsigned char* wl = lds + 98304 + (size_t)kg * 256 + l15 * 16;
        MFMA7(ahi, alo, wb, wl, ax0, ax1, ax2);
      }
#pragma unroll
      for (int kk = 0; kk < 4; ++kk) {                     // hg = h2_{T-2} . Wh2
        int kg = wv * 16 + kk * 4 + q;
        bf16x8 ahi = *(const bf16x8*)(hs + kg * 8);
        bf16x8 alo = *(const bf16x8*)(hs + 32768 + kg * 8);
        const unsigned char* wb = lds + 49152 + (size_t)kg * 768 + l15 * 16;
        const unsigned char* wl = lds + 98304 + 16384 + (size_t)kg * 256 + l15 * 16;
        MFMA7(ahi, alo, wb, wl, ah0, ah1, ah2);
      }
      REDUCE_AND_GATE();
      unsigned short hi = f2bf(hn);
      unsigned short lo = f2bf(hn - bf2f(hi));
      unsigned short* hd = h2 + (size_t)((T - 1) & 3) * 65536 + (size_t)row_g * 512 + col_g;
      hd[0] = hi; hd[32768] = lo;
      if (T == 1025) h2f[(size_t)row_g * 512 + col_g] = hn;
      __syncthreads();
      if (tid == 0) {
        __threadfence();
        __hip_atomic_fetch_add(c2 + T, 1, __ATOMIC_RELAXED, __HIP_MEMORY_SCOPE_AGENT);
      }
    }
  }
#undef MFMA7
#undef REDUCE_AND_GATE
}

// ============================================================================
// Backward direction, first scan step only (h0=0): out = (1-sig(xg1))*tanh(xg2).
// ============================================================================
__global__ __launch_bounds__(256) void gru_bstep(const float* __restrict__ inp, long rstride,
                                                 const float* __restrict__ Wi,
                                                 const float* __restrict__ bias,
                                                 float* __restrict__ out) {
  __shared__ float a[8192];                  // [16][512]
  int tid = threadIdx.x;
  int bg = blockIdx.x >> 4, cg = blockIdx.x & 15;
  for (int j = 0; j < 32; ++j) {
    int idx = j * 256 + tid;
    int r = idx >> 9, k = idx & 511;
    a[idx] = inp[(size_t)(bg * 16 + r) * rstride + k];
  }
  __syncthreads();
  int col = cg * 32 + (tid & 31);
  int r0 = tid >> 5;
  float z0 = bias[512 + col], z1 = z0;
  float n0 = bias[1024 + col], n1 = n0;
  const float* W1 = Wi + (size_t)512 * 512;
  const float* W2 = Wi + (size_t)2 * 512 * 512;
  for (int k = 0; k < 512; ++k) {
    float wz = W1[(size_t)k * 512 + col];
    float wn = W2[(size_t)k * 512 + col];
    float a0 = a[r0 * 512 + k], a1 = a[(r0 + 8) * 512 + k];
    z0 += a0 * wz; z1 += a1 * wz;
    n0 += a0 * wn; n1 += a1 * wn;
  }
  float s0 = sigmoidf_(z0), s1 = sigmoidf_(z1);
  out[(size_t)(bg * 16 + r0) * 512 + col]     = (1.f - s0) * tanhf(n0);
  out[(size_t)(bg * 16 + r0 + 8) * 512 + col] = (1.f - s1) * tanhf(n1);
}

__global__ __launch_bounds__(256) void fc_kernel(const float* __restrict__ h2f,
                                                 const float* __restrict__ hb2,
                                                 const float* __restrict__ fcw,
                                                 const float* __restrict__ fcb,
                                                 float* __restrict__ out) {
  __shared__ float a[16384];                 // [16][1024]
  int tid = threadIdx.x;
  int bg = blockIdx.x >> 4, cg = blockIdx.x & 15;
  for (int j = 0; j < 32; ++j) {
    int idx = j * 256 + tid;
    int r = idx >> 9, k = idx & 511;
    a[r * 1024 + k]       = h2f[(size_t)(bg * 16 + r) * 512 + k];
    a[r * 1024 + 512 + k] = hb2[(size_t)(bg * 16 + r) * 512 + k];
  }
  __syncthreads();
  int col = cg * 32 + (tid & 31);
  int r0 = tid >> 5;
  float s0 = fcb[col], s1 = fcb[col];
  for (int k = 0; k < 1024; ++k) {
    float wvv = fcw[(size_t)k * 512 + col];
    s0 += a[r0 * 1024 + k] * wvv;
    s1 += a[(r0 + 8) * 1024 + k] * wvv;
  }
  out[(size_t)(bg * 16 + r0) * 512 + col]     = s0;
  out[(size_t)(bg * 16 + r0 + 8) * 512 + col] = s1;
}

extern "C" void kernel_launch(void* const* d_in, const int* in_sizes, int n_in,
                              void* d_out, int out_size, void* d_ws, size_t ws_size,
                              hipStream_t stream) {
  const float* x   = (const float*)d_in[0];
  const float* Wi  = (const float*)d_in[1];
  const float* Wh  = (const float*)d_in[2];
  const float* b   = (const float*)d_in[3];
  const float* fcw = (const float*)d_in[4];
  const float* fcb = (const float*)d_in[5];
  float* out = (float*)d_out;
  unsigned char* ws = (unsigned char*)d_ws;
  if (ws_size < WS_NEED) return;   // visible failure (poisoned out), not corruption

  prep_weights<<<16384, 256, 0, stream>>>(Wi, Wh, (unsigned short*)(ws + OFF_WIMG));
  init_state<<<1024, 256, 0, stream>>>((uint32_t*)(ws + OFF_H1), (int*)(ws + OFF_CNT));
  gru_persistent<<<256, 256, 0, stream>>>(x, b, ws);
  gru_bstep<<<64, 256, 0, stream>>>(x + (size_t)1023 * 512, (long)Ss * Ii,
                                    Wi + (size_t)3 * 512 * 512, b + 3 * 512,
                                    (float*)(ws + OFF_HB1));
  gru_bstep<<<64, 256, 0, stream>>>((const float*)(ws + OFF_HB1), 512L,
                                    Wi + (size_t)9 * 512 * 512, b + 9 * 512,
                                    (float*)(ws + OFF_HB2));
  fc_kernel<<<64, 256, 0, stream>>>((const float*)(ws + OFF_H2F), (const float*)(ws + OFF_HB2),
                                    fcw, fcb, out);
}

// Round 3
// 15366.705 us; speedup vs baseline: 1.2588x; 1.2588x over previous
//
#include <hip/hip_runtime.h>
#include <cstdint>
#include <cmath>

// ============================================================================
// Bidirectional 2-layer GRU, B=64 S=1024 I=H=512, output = last-step concat @ fc.
//   forward : 1024-step recurrence, persistent kernel, 64 blocks (2 layers x
//             32 col-slices), each block = all 64 rows x 16 cols, 4 waves = 4
//             row-fragments, gates in-register (no cross-wave reduce).
//   backward: only scan index 0 survives => ONE step per layer with h0=0.
// Sync: per-producer monotonic flag words flags[layer*32+slice]=T; release
// fetch_max / relaxed 64-lane poll + __all + acquire fence. Sticky timeout
// poison => never hangs. Wh-side B-fragments live in VGPRs (192 regs); only
// the non-recurrent Wi GEMMs read B from LDS.
// ============================================================================

typedef __attribute__((ext_vector_type(8))) short bf16x8;
typedef __attribute__((ext_vector_type(4))) float f32x4;
typedef __attribute__((ext_vector_type(4))) unsigned int u32x4;

#define DEV static __device__ __forceinline__

DEV unsigned short f2bf(float f) {
  union { float f; uint32_t u; } v; v.f = f;
  uint32_t u = v.u;
  return (unsigned short)((u + (((u >> 16) & 1u) + 0x7fffu)) >> 16);
}
DEV float bf2f(unsigned short h) {
  union { uint32_t u; float f; } v; v.u = ((uint32_t)h) << 16;
  return v.f;
}
DEV float fsig(float x)  { return 1.f / (1.f + __expf(-x)); }
DEV float ftanh(float x) { return 2.f / (1.f + __expf(-2.f * x)) - 1.f; }

static constexpr int Ss = 1024, Ii = 512;

// ---- workspace layout (bytes) ----
static constexpr size_t WIMG_PER_LS = 131072;                  // 96KB hi + 32KB n-lo
static constexpr size_t OFF_WIMG = 0;
static constexpr size_t WIMG_BYTES = (size_t)64 * WIMG_PER_LS; // 8 MB
static constexpr size_t OFF_H1  = OFF_WIMG + WIMG_BYTES;       // 4 planes x (hi|lo) [64][512] bf16
static constexpr size_t OFF_H2  = OFF_H1 + 524288;
static constexpr size_t OFF_FLG = OFF_H2 + 524288;             // int[64] (+pad)
static constexpr size_t OFF_H2F = OFF_FLG + 1024;              // f32 [64][512]
static constexpr size_t OFF_HB1 = OFF_H2F + 131072;
static constexpr size_t OFF_HB2 = OFF_HB1 + 131072;
static constexpr size_t WS_NEED = OFF_HB2 + 131072;

// ============================================================================
// Weight prep (unchanged layout from round 2): per (layer,slice) 65536 bf16:
//   [0,49152)     hi : m(2:Wi,Wh)*24576 + kg(64)*384 + (g*16+cc)*8 + kr(8)
//   [49152,65536) n-gate lo residual: m*8192 + kg*128 + cc*8 + kr
// ============================================================================
__global__ __launch_bounds__(256) void prep_weights(const float* __restrict__ Wi,
                                                    const float* __restrict__ Wh,
                                                    unsigned short* __restrict__ img) {
  uint32_t idx = blockIdx.x * 256 + threadIdx.x;          // < 4,194,304
  uint32_t ls = idx >> 16;                                // layer*32+slice
  uint32_t off = idx & 65535u;
  int l = (int)(ls >> 5), s = (int)(ls & 31);
  int m, g, cc, kg, kr;
  bool lo = off >= 49152u;
  if (!lo) {
    m = (int)(off / 24576u); uint32_t r = off % 24576u;
    kg = (int)(r / 384u); r %= 384u;
    int c = (int)(r >> 3); kr = (int)(r & 7u);
    g = c >> 4; cc = c & 15;
  } else {
    uint32_t o2 = off - 49152u;
    m = (int)(o2 >> 13); uint32_t r = o2 & 8191u;
    kg = (int)(r >> 7); r &= 127u;
    cc = (int)(r >> 3); kr = (int)(r & 7u);
    g = 2;
  }
  int h = s * 16 + cc, k = kg * 8 + kr;
  const float* W = m ? Wh : Wi;                           // [L][D][3][512][512], d=0
  float v = W[((size_t)(l * 6 + g) * 512 + k) * 512 + h];
  unsigned short hv = f2bf(v);
  if (lo) hv = f2bf(v - bf2f(hv));
  img[(size_t)ls * 65536 + off] = hv;
}

// zero h rings; flags: layer0 = 0, layer1 = 1 (its step-1 is a virtual no-op)
__global__ __launch_bounds__(256) void init_state(uint32_t* __restrict__ hz,
                                                  int* __restrict__ flg) {
  int tid = blockIdx.x * 256 + threadIdx.x;
  if (tid < 262144) hz[tid] = 0u;                         // h1+h2 = 1MB
  if (tid < 64) flg[tid] = (tid >= 32) ? 1 : 0;
}

#define MFMA(AA, BB, CC) CC = __builtin_amdgcn_mfma_f32_16x16x32_bf16(AA, BB, CC, 0, 0, 0)

// hang-proof wait: lanes 0-31 check flags[0][lane] >= tA, lanes 32-63 check
// flags[1][lane-32] >= tB; on timeout every lane sticky-poisons its flag word.
#define WAIT2(TA, TB)                                                              \
  {                                                                                \
    const int tgt_ = (lane < 32) ? (TA) : (TB);                                    \
    int spins_ = 0;                                                                \
    for (;;) {                                                                     \
      int v_ = __hip_atomic_load(pollp, __ATOMIC_RELAXED, __HIP_MEMORY_SCOPE_AGENT); \
      if (__all(v_ >= tgt_)) break;                                                \
      __builtin_amdgcn_s_sleep(1);                                                 \
      if (++spins_ > (1 << 20)) {                                                  \
        __hip_atomic_fetch_max((int*)pollp, 0x40000000, __ATOMIC_RELAXED,          \
                               __HIP_MEMORY_SCOPE_AGENT);                          \
        break;                                                                     \
      }                                                                            \
    }                                                                              \
    __builtin_amdgcn_fence(__ATOMIC_ACQUIRE, "agent");                             \
  }

// ============================================================================
// Persistent forward recurrence. LDS = 128KB weight image only.
// ============================================================================
__global__ __launch_bounds__(256, 1) void gru_persistent(const float* __restrict__ x,
                                                         const float* __restrict__ bias,
                                                         unsigned char* __restrict__ ws) {
  __shared__ unsigned char lds[131072];
  const int tid = threadIdx.x, lane = tid & 63, wv = tid >> 6;
  const int bid = blockIdx.x;
  const int layer = bid >> 5, slice = bid & 31;
  const int l15 = lane & 15, q = lane >> 4;

  { // stage this block's 128KB weight image into LDS once
    const u32x4* src = (const u32x4*)(ws + OFF_WIMG + (size_t)(layer * 32 + slice) * WIMG_PER_LS);
    u32x4* dst = (u32x4*)lds;
    for (int i = tid; i < 8192; i += 256) dst[i] = src[i];
  }
  __syncthreads();

  // cache recurrent-side (Wh, m=1) hi B-fragments in registers: 16 kk x 3 gates
  bf16x8 hB[48];
#pragma unroll
  for (int kk = 0; kk < 16; ++kk) {
    const int kg = kk * 4 + q;
    const unsigned char* wb = lds + 49152 + (size_t)kg * 768 + (size_t)l15 * 16;
    hB[kk * 3 + 0] = *(const bf16x8*)(wb);
    hB[kk * 3 + 1] = *(const bf16x8*)(wb + 256);
    hB[kk * 3 + 2] = *(const bf16x8*)(wb + 512);
  }

  unsigned short* h1 = (unsigned short*)(ws + OFF_H1);
  unsigned short* h2 = (unsigned short*)(ws + OFF_H2);
  int* flg = (int*)(ws + OFF_FLG);
  float* h2f = (float*)(ws + OFF_H2F);

  const int colg = slice * 16 + l15;
  const int row0 = wv * 16 + q * 4;            // first of this lane's 4 C rows
  const float b0 = bias[(size_t)(layer * 6 + 0) * 512 + colg];
  const float b1 = bias[(size_t)(layer * 6 + 1) * 512 + colg];
  const float b2 = bias[(size_t)(layer * 6 + 2) * 512 + colg];

  int* myflag = flg + layer * 32 + slice;
  const int* pollp = flg + lane;
  f32x4 hprev{0.f, 0.f, 0.f, 0.f};

  if (layer == 0) {
    const float* xr0 = x + (size_t)(wv * 16 + l15) * Ss * Ii;   // this lane's A row
    for (int T = 1; T <= 1024; ++T) {
      f32x4 ax0{}, ax1{}, ax2{}, ah0{}, ah1{}, ah2{};
      // ---- x_t . Wi1 : A from global f32 (hi/lo built in-reg), B from LDS ----
      const float* xr = xr0 + (size_t)(T - 1) * Ii;
#pragma unroll 4
      for (int kk = 0; kk < 16; ++kk) {
        const int kg = kk * 4 + q;
        f32x4 va = *(const f32x4*)(xr + kg * 8);
        f32x4 vb = *(const f32x4*)(xr + kg * 8 + 4);
        bf16x8 ahi, alo;
#pragma unroll
        for (int e = 0; e < 4; ++e) {
          unsigned short ha = f2bf(va[e]);
          ((unsigned short*)&ahi)[e] = ha;
          ((unsigned short*)&alo)[e] = f2bf(va[e] - bf2f(ha));
          unsigned short hb_ = f2bf(vb[e]);
          ((unsigned short*)&ahi)[e + 4] = hb_;
          ((unsigned short*)&alo)[e + 4] = f2bf(vb[e] - bf2f(hb_));
        }
        const unsigned char* wb = lds + (size_t)kg * 768 + (size_t)l15 * 16;
        bf16x8 q0 = *(const bf16x8*)(wb);
        bf16x8 q1 = *(const bf16x8*)(wb + 256);
        bf16x8 q2 = *(const bf16x8*)(wb + 512);
        bf16x8 ql = *(const bf16x8*)(lds + 98304 + (size_t)kg * 256 + (size_t)l15 * 16);
        MFMA(ahi, q0, ax0); MFMA(alo, q0, ax0);
        MFMA(ahi, q1, ax1); MFMA(alo, q1, ax1);
        MFMA(ahi, q2, ax2); MFMA(alo, q2, ax2);
        MFMA(ahi, ql, ax2);
      }
      // ---- wait: h1_{T-1} complete; layer-2 past reading h1_{T-4} ----
      WAIT2(T - 1, T - 3);
      // ---- h1_{T-1} . Wh1 : A from global bf16 hi/lo, B from registers ----
      const unsigned short* hsrc = h1 + (size_t)((T - 1) & 3) * 65536 + (size_t)(wv * 16 + l15) * 512;
#pragma unroll
      for (int kk = 0; kk < 16; ++kk) {
        const int kg = kk * 4 + q;
        bf16x8 ahi = *(const bf16x8*)(hsrc + kg * 8);
        bf16x8 alo = *(const bf16x8*)(hsrc + 32768 + kg * 8);
        bf16x8 ql = *(const bf16x8*)(lds + 98304 + 16384 + (size_t)kg * 256 + (size_t)l15 * 16);
        MFMA(ahi, hB[kk * 3 + 0], ah0); MFMA(alo, hB[kk * 3 + 0], ah0);
        MFMA(ahi, hB[kk * 3 + 1], ah1); MFMA(alo, hB[kk * 3 + 1], ah1);
        MFMA(ahi, hB[kk * 3 + 2], ah2); MFMA(alo, hB[kk * 3 + 2], ah2);
        MFMA(ahi, ql, ah2);
      }
      // ---- gates in-register; store h1_T ----
      unsigned short* hd = h1 + (size_t)(T & 3) * 65536;
#pragma unroll
      for (int e = 0; e < 4; ++e) {
        float rr = fsig(ax0[e] + ah0[e] + b0);
        float zz = fsig(ax1[e] + ah1[e] + b1);
        float nn = ftanh(ax2[e] + b2 + rr * ah2[e]);
        float hn = (1.f - zz) * nn + zz * hprev[e];
        hprev[e] = hn;
        unsigned short hi = f2bf(hn), lo = f2bf(hn - bf2f(hi));
        size_t o = (size_t)(row0 + e) * 512 + colg;
        hd[o] = hi; hd[o + 32768] = lo;
      }
      __syncthreads();                          // all waves' stores drained
      if (tid == 0)
        __hip_atomic_fetch_max(myflag, T, __ATOMIC_RELEASE, __HIP_MEMORY_SCOPE_AGENT);
    }
  } else {
    // layer 2, one step behind: at iter T computes h2_{T-1}
    for (int T = 2; T <= 1025; ++T) {
      WAIT2(T - 1, T - 1);
      f32x4 ax0{}, ax1{}, ax2{}, ah0{}, ah1{}, ah2{};
      const unsigned short* as = h1 + (size_t)((T - 1) & 3) * 65536 + (size_t)(wv * 16 + l15) * 512;
      const unsigned short* hsrc = h2 + (size_t)((T - 2) & 3) * 65536 + (size_t)(wv * 16 + l15) * 512;
      // ---- h1_{T-1} . Wi2 : B from LDS ----
#pragma unroll 4
      for (int kk = 0; kk < 16; ++kk) {
        const int kg = kk * 4 + q;
        bf16x8 ahi = *(const bf16x8*)(as + kg * 8);
        bf16x8 alo = *(const bf16x8*)(as + 32768 + kg * 8);
        const unsigned char* wb = lds + (size_t)kg * 768 + (size_t)l15 * 16;
        bf16x8 q0 = *(const bf16x8*)(wb);
        bf16x8 q1 = *(const bf16x8*)(wb + 256);
        bf16x8 q2 = *(const bf16x8*)(wb + 512);
        bf16x8 ql = *(const bf16x8*)(lds + 98304 + (size_t)kg * 256 + (size_t)l15 * 16);
        MFMA(ahi, q0, ax0); MFMA(alo, q0, ax0);
        MFMA(ahi, q1, ax1); MFMA(alo, q1, ax1);
        MFMA(ahi, q2, ax2); MFMA(alo, q2, ax2);
        MFMA(ahi, ql, ax2);
      }
      // ---- h2_{T-2} . Wh2 : B from registers ----
#pragma unroll
      for (int kk = 0; kk < 16; ++kk) {
        const int kg = kk * 4 + q;
        bf16x8 ahi = *(const bf16x8*)(hsrc + kg * 8);
        bf16x8 alo = *(const bf16x8*)(hsrc + 32768 + kg * 8);
        bf16x8 ql = *(const bf16x8*)(lds + 98304 + 16384 + (size_t)kg * 256 + (size_t)l15 * 16);
        MFMA(ahi, hB[kk * 3 + 0], ah0); MFMA(alo, hB[kk * 3 + 0], ah0);
        MFMA(ahi, hB[kk * 3 + 1], ah1); MFMA(alo, hB[kk * 3 + 1], ah1);
        MFMA(ahi, hB[kk * 3 + 2], ah2); MFMA(alo, hB[kk * 3 + 2], ah2);
        MFMA(ahi, ql, ah2);
      }
      unsigned short* hd = h2 + (size_t)((T - 1) & 3) * 65536;
#pragma unroll
      for (int e = 0; e < 4; ++e) {
        float rr = fsig(ax0[e] + ah0[e] + b0);
        float zz = fsig(ax1[e] + ah1[e] + b1);
        float nn = ftanh(ax2[e] + b2 + rr * ah2[e]);
        float hn = (1.f - zz) * nn + zz * hprev[e];
        hprev[e] = hn;
        unsigned short hi = f2bf(hn), lo = f2bf(hn - bf2f(hi));
        size_t o = (size_t)(row0 + e) * 512 + colg;
        hd[o] = hi; hd[o + 32768] = lo;
        if (T == 1025) h2f[o] = hn;
      }
      __syncthreads();
      if (tid == 0)
        __hip_atomic_fetch_max(myflag, T, __ATOMIC_RELEASE, __HIP_MEMORY_SCOPE_AGENT);
    }
  }
}

// ============================================================================
// Backward direction, first scan step only (h0=0): out = (1-sig(xg1))*tanh(xg2).
// ============================================================================
__global__ __launch_bounds__(256) void gru_bstep(const float* __restrict__ inp, long rstride,
                                                 const float* __restrict__ Wi,
                                                 const float* __restrict__ bias,
                                                 float* __restrict__ out) {
  __shared__ float a[8192];                  // [16][512]
  int tid = threadIdx.x;
  int bg = blockIdx.x >> 4, cg = blockIdx.x & 15;
  for (int j = 0; j < 32; ++j) {
    int idx = j * 256 + tid;
    int r = idx >> 9, k = idx & 511;
    a[idx] = inp[(size_t)(bg * 16 + r) * rstride + k];
  }
  __syncthreads();
  int col = cg * 32 + (tid & 31);
  int r0 = tid >> 5;
  float z0 = bias[512 + col], z1 = z0;
  float n0 = bias[1024 + col], n1 = n0;
  const float* W1 = Wi + (size_t)512 * 512;
  const float* W2 = Wi + (size_t)2 * 512 * 512;
  for (int k = 0; k < 512; ++k) {
    float wz = W1[(size_t)k * 512 + col];
    float wn = W2[(size_t)k * 512 + col];
    float a0 = a[r0 * 512 + k], a1 = a[(r0 + 8) * 512 + k];
    z0 += a0 * wz; z1 += a1 * wz;
    n0 += a0 * wn; n1 += a1 * wn;
  }
  float s0 = fsig(z0), s1 = fsig(z1);
  out[(size_t)(bg * 16 + r0) * 512 + col]     = (1.f - s0) * ftanh(n0);
  out[(size_t)(bg * 16 + r0 + 8) * 512 + col] = (1.f - s1) * ftanh(n1);
}

__global__ __launch_bounds__(256) void fc_kernel(const float* __restrict__ h2f,
                                                 const float* __restrict__ hb2,
                                                 const float* __restrict__ fcw,
                                                 const float* __restrict__ fcb,
                                                 float* __restrict__ out) {
  __shared__ float a[16384];                 // [16][1024]
  int tid = threadIdx.x;
  int bg = blockIdx.x >> 4, cg = blockIdx.x & 15;
  for (int j = 0; j < 32; ++j) {
    int idx = j * 256 + tid;
    int r = idx >> 9, k = idx & 511;
    a[r * 1024 + k]       = h2f[(size_t)(bg * 16 + r) * 512 + k];
    a[r * 1024 + 512 + k] = hb2[(size_t)(bg * 16 + r) * 512 + k];
  }
  __syncthreads();
  int col = cg * 32 + (tid & 31);
  int r0 = tid >> 5;
  float s0 = fcb[col], s1 = fcb[col];
  for (int k = 0; k < 1024; ++k) {
    float wvv = fcw[(size_t)k * 512 + col];
    s0 += a[r0 * 1024 + k] * wvv;
    s1 += a[(r0 + 8) * 1024 + k] * wvv;
  }
  out[(size_t)(bg * 16 + r0) * 512 + col]     = s0;
  out[(size_t)(bg * 16 + r0 + 8) * 512 + col] = s1;
}

extern "C" void kernel_launch(void* const* d_in, const int* in_sizes, int n_in,
                              void* d_out, int out_size, void* d_ws, size_t ws_size,
                              hipStream_t stream) {
  const float* x   = (const float*)d_in[0];
  const float* Wi  = (const float*)d_in[1];
  const float* Wh  = (const float*)d_in[2];
  const float* b   = (const float*)d_in[3];
  const float* fcw = (const float*)d_in[4];
  const float* fcb = (const float*)d_in[5];
  float* out = (float*)d_out;
  unsigned char* ws = (unsigned char*)d_ws;
  if (ws_size < WS_NEED) return;   // visible failure (poisoned out), not corruption

  prep_weights<<<16384, 256, 0, stream>>>(Wi, Wh, (unsigned short*)(ws + OFF_WIMG));
  init_state<<<1024, 256, 0, stream>>>((uint32_t*)(ws + OFF_H1), (int*)(ws + OFF_FLG));
  gru_persistent<<<64, 256, 0, stream>>>(x, b, ws);
  gru_bstep<<<64, 256, 0, stream>>>(x + (size_t)1023 * 512, (long)Ss * Ii,
                                    Wi + (size_t)3 * 512 * 512, b + 3 * 512,
                                    (float*)(ws + OFF_HB1));
  gru_bstep<<<64, 256, 0, stream>>>((const float*)(ws + OFF_HB1), 512L,
                                    Wi + (size_t)9 * 512 * 512, b + 9 * 512,
                                    (float*)(ws + OFF_HB2));
  fc_kernel<<<64, 256, 0, stream>>>((const float*)(ws + OFF_H2F), (const float*)(ws + OFF_HB2),
                                    fcw, fcb, out);
}